// Round 1
// baseline (68.906 us; speedup 1.0000x reference)
//
#include <hip/hip_runtime.h>

// 21-qubit HEA, fp32, all-real. ONE kernel, 256 blocks x 512 threads.
// R9: move the U1/U2 boundary from bit 13 to bit 12 so the grid doubles
// (128 -> 256 blocks; all 256 CUs active) and per-thread state halves
// (v[32] -> v[16], LDS 67.6KB -> 34KB).
// Factorization: U_total = U2' * U1' * |init>, where
//   U1' = {RY2 q0..q8, C0..C7, RY3 q0..q7}    acts only on bits 20..12,
//   U2' = {RY2 q9..q20, C8..C19, RY3 q8..q20} acts only on bits 12..0.
// Commutation proof (disjoint qubits): RY2 q9..20 (bits 11..0) move right
// past C0..C7 (bits 20..12); RY3 q0..7 (bits 20..13) move left past
// C8..C19 (bits 12..0).
// init (layer1+chain1): amp(x) = Prod_b sel(p_{20-b}, x_b^x_{b+1}) (x21=0)
//   = F'(z') * sel(p9, x11 ^ z'_0) * G'(L'),
// z' = x20..x12 (9 bits, z'_j = x_{12+j}), L' = x11..x0.
// F'(z') = sel(p0, z'_8) * Prod_{j=0..7} sel(p_{8-j}, z'_j ^ z'_{j+1}),
// G'(L') = Prod_{b=0..10} sel(p_{20-b}, L'_b ^ L'_{b+1}).
// Block fixes bid = x20..x13 (8 bits). From U1' need a(x12,c) =
// (U1' Phi_c)(z'*), z'* = (bid<<1)|x12, Phi_c(z') = F'(z')[z'_0==c]:
// a 1024-dim (c,z') sim redundant per wave: lane = (c<<5)|(z'>>4),
// regs e = z'_3..z'_0 (16); z'-bits 4..8 via shfl, 0..3 in-reg.
// W[x12][x11] = a(x12,0)*sel(p9,x11) + a(x12,1)*sel(p9,~x11);
// v_init = W * G'(L'); then U2' over 4 layouts (1-bit overlap):
//   A: regs x12..x9, tid=x8..x0   : RY2 p30..32; C8..C10;  RY3 p50..52
//   B: regs x9..x6,  tid=x12..x10,x5..x0: RY2 p33..35; C11..C13; RY3 p53..55
//   C: regs x6..x3,  tid=x12..x7,x2..x0 : RY2 p36..38; C14..C16; RY3 p56..58
//   D: regs x3..x0,  tid=x12..x4  : RY2 p39..41; C17..C19; RY3 p59..62
// Ledger: RY2 q9..20 = p30..41 (each precedes the first CNOT touching its
// bit: p33/bit8 before C11, p36/bit5 before C14, p39..41/bits2..0 before
// C17..19 -- all legal by disjoint-bit commutation with earlier CNOTs);
// RY3 q8..20 = p50..62 (each follows the last CNOT touching its bit).
// qubit q <-> bit 20-q; params RY1 q->p[q], RY2 q->p[21+q], RY3 q->p[42+q].
// Norm == 1 by unitarity.

#define NQ 21
#define NSTATE (1 << NQ)
#define SW(t) ((t) + ((t) >> 5))  // LDS anti-conflict: +1 word / 32 words

typedef float f32x4 __attribute__((ext_vector_type(4)));

__device__ __forceinline__ float sel(const float* cs, const float* sn, int i,
                                     int bit) {
  return bit ? sn[i] : cs[i];
}

template <int BIT, int N>
__device__ __forceinline__ void ry_bf(float (&v)[N], float c, float s) {
#pragma unroll
  for (int m = 0; m < N; ++m)
    if ((m & (1 << BIT)) == 0) {
      float a = v[m], b = v[m | (1 << BIT)];
      v[m] = c * a - s * b;
      v[m | (1 << BIT)] = s * a + c * b;
    }
}

template <int CBIT, int TBIT, int N>
__device__ __forceinline__ void cnot_rr(float (&v)[N]) {
#pragma unroll
  for (int m = 0; m < N; ++m)
    if ((m & (1 << CBIT)) && !(m & (1 << TBIT))) {
      float t = v[m];
      v[m] = v[m | (1 << TBIT)];
      v[m | (1 << TBIT)] = t;
    }
}

// CNOT with control outside the register index (cond), target reg bit.
template <int TBIT, int N>
__device__ __forceinline__ void cswap_bf(float (&v)[N], bool cond) {
#pragma unroll
  for (int m = 0; m < N; ++m)
    if ((m & (1 << TBIT)) == 0) {
      float a = v[m], b = v[m | (1 << TBIT)];
      v[m] = cond ? b : a;
      v[m | (1 << TBIT)] = cond ? a : b;
    }
}

// RY on a z-bit living in the LANE index (shfl butterfly).
template <int MASK, int N>
__device__ __forceinline__ void ry_shfl(float (&u)[N], float c, float s,
                                        int lane) {
  const float ss = (lane & MASK) ? s : -s;
#pragma unroll
  for (int e = 0; e < N; ++e) {
    float w = __shfl_xor(u[e], MASK);
    u[e] = c * u[e] + ss * w;
  }
}

// CNOT: ctrl lane-bit mask CMASK, tgt lane-bit mask TMASK.
template <int CMASK, int TMASK, int N>
__device__ __forceinline__ void cnot_shfl(float (&u)[N], int lane) {
  const bool ctrl = (lane & CMASK) != 0;
#pragma unroll
  for (int e = 0; e < N; ++e) {
    float w = __shfl_xor(u[e], TMASK);
    u[e] = ctrl ? w : u[e];
  }
}

__global__ __launch_bounds__(512) void fused(const float* __restrict__ p,
                                             float* __restrict__ out,
                                             int outmode) {
  __shared__ float cs[63], sn[63];
  __shared__ float ex[8448];    // 8192 + swizzle pad (max SW(8191)=8446)
  const int tid = threadIdx.x;  // 9 bits
  const int bid = blockIdx.x;   // 8 bits: bid_i = x_{13+i}
  if (tid < 63) {
    float h = 0.5f * p[tid];
    cs[tid] = cosf(h);
    sn[tid] = sinf(h);
  }
  __syncthreads();

  // ========== U1' pre-sim: 1024-dim (c,z'), redundant per wave ==========
  const int lane = tid & 63;  // lane = (c<<5) | (z'>>4); regs e = z'_3..z'_0
  float u[16];
  {
    const int zh = (lane & 31) << 4;
    const int c = lane >> 5;
#pragma unroll
    for (int e = 0; e < 16; ++e) {
      const int z = zh | e;          // 9-bit z'
      const int gz = z ^ (z >> 1);   // bit j = z'_j ^ z'_{j+1} (j<8)
      float F = sel(cs, sn, 0, (z >> 8) & 1);
#pragma unroll
      for (int j = 0; j < 8; ++j) F *= sel(cs, sn, 8 - j, (gz >> j) & 1);
      u[e] = ((z & 1) == c) ? F : 0.0f;
    }
  }
  // RY2 q0..q8 (p21..p29) on z'_8..z'_0
  ry_shfl<16>(u, cs[21], sn[21], lane);
  ry_shfl<8>(u, cs[22], sn[22], lane);
  ry_shfl<4>(u, cs[23], sn[23], lane);
  ry_shfl<2>(u, cs[24], sn[24], lane);
  ry_shfl<1>(u, cs[25], sn[25], lane);
  ry_bf<3>(u, cs[26], sn[26]);
  ry_bf<2>(u, cs[27], sn[27]);
  ry_bf<1>(u, cs[28], sn[28]);
  ry_bf<0>(u, cs[29], sn[29]);
  // C0..C7 down the chain (C_q: ctrl z'_{8-q}, tgt z'_{7-q})
  cnot_shfl<16, 8>(u, lane);        // C0
  cnot_shfl<8, 4>(u, lane);         // C1
  cnot_shfl<4, 2>(u, lane);         // C2
  cnot_shfl<2, 1>(u, lane);         // C3
  cswap_bf<3>(u, (lane & 1) != 0);  // C4: ctrl z'_4 (lane0), tgt z'_3 (reg3)
  cnot_rr<3, 2>(u);                 // C5
  cnot_rr<2, 1>(u);                 // C6
  cnot_rr<1, 0>(u);                 // C7
  // RY3 q0..q7 (p42..p49) on z'_8..z'_1
  ry_shfl<16>(u, cs[42], sn[42], lane);
  ry_shfl<8>(u, cs[43], sn[43], lane);
  ry_shfl<4>(u, cs[44], sn[44], lane);
  ry_shfl<2>(u, cs[45], sn[45], lane);
  ry_shfl<1>(u, cs[46], sn[46], lane);
  ry_bf<3>(u, cs[47], sn[47]);
  ry_bf<2>(u, cs[48], sn[48]);
  ry_bf<1>(u, cs[49], sn[49]);

  // Extract a(x12,c): z'* = (bid<<1)|x12 -> lane* = (c<<5)|(bid>>3),
  // reg e* = ((bid&7)<<1)|x12 (bid-uniform select + shfl broadcast).
  const int b7 = bid & 7;
  float ue0 = u[0], ue1 = u[1];
#pragma unroll
  for (int k = 1; k < 8; ++k) {
    ue0 = (b7 == k) ? u[2 * k] : ue0;
    ue1 = (b7 == k) ? u[2 * k + 1] : ue1;
  }
  const int l0 = bid >> 3;
  const float a00 = __shfl(ue0, l0);       // x12=0, c=0
  const float a01 = __shfl(ue0, 32 | l0);  // x12=0, c=1
  const float a10 = __shfl(ue1, l0);       // x12=1, c=0
  const float a11 = __shfl(ue1, 32 | l0);  // x12=1, c=1
  float W[2][2];                           // W[x12][x11], boundary p9
  W[0][0] = a00 * cs[9] + a01 * sn[9];
  W[0][1] = a00 * sn[9] + a01 * cs[9];
  W[1][0] = a10 * cs[9] + a11 * sn[9];
  W[1][1] = a10 * sn[9] + a11 * cs[9];

  // ========== Phase 2 (U2' on bits 12..0) ==========
  float v[16];
  // ---- Layout A: regs r_j = x_{9+j} (r3=x12..r0=x9); tid = x8..x0.
  {
    const int gt = tid ^ (tid >> 1);  // bit b = x_b ^ x_{b+1}, b<8
    float tcommon = 1.0f;
#pragma unroll
    for (int b = 0; b < 8; ++b)
      tcommon *= sel(cs, sn, 20 - b, (gt >> b) & 1);
    const int t8 = (tid >> 8) & 1;  // x8
#pragma unroll
    for (int r = 0; r < 16; ++r) {
      const int gr = r ^ (r >> 1);  // gr_0 = x9^x10, gr_1 = x10^x11
      float prod = tcommon * W[(r >> 3) & 1][(r >> 2) & 1];
      prod *= sel(cs, sn, 12, t8 ^ (r & 1));  // s8 = x8 ^ x9
      prod *= sel(cs, sn, 11, gr & 1);        // s9
      prod *= sel(cs, sn, 10, (gr >> 1) & 1); // s10 (s11 folded into W)
      v[r] = prod;
    }
  }

  // RY2 q9..q11 (p30..32 on bits 11..9 = r2..r0); C8..C10;
  // RY3 q8..q10 (p50..52 on bits 12..10 = r3..r1)
  ry_bf<2>(v, cs[30], sn[30]);
  ry_bf<1>(v, cs[31], sn[31]);
  ry_bf<0>(v, cs[32], sn[32]);
  cnot_rr<3, 2>(v);  // C8:  ctrl bit12, tgt bit11
  cnot_rr<2, 1>(v);  // C9
  cnot_rr<1, 0>(v);  // C10
  ry_bf<3>(v, cs[50], sn[50]);
  ry_bf<2>(v, cs[51], sn[51]);
  ry_bf<1>(v, cs[52], sn[52]);

  // Exchange A -> B. Canonical t = x12..x0.
#pragma unroll
  for (int r = 0; r < 16; ++r) ex[SW((r << 9) | tid)] = v[r];
  __syncthreads();
  // ---- Layout B: regs r_j = x_{6+j}; tid[8:6]=x12..x10, tid[5:0]=x5..x0
#pragma unroll
  for (int r = 0; r < 16; ++r)
    v[r] = ex[SW(((tid >> 6) << 10) | (r << 6) | (tid & 63))];
  __syncthreads();

  // RY2 q12..q14 (p33..35 on bits 8..6 = r2..r0); C11..C13;
  // RY3 q11..q13 (p53..55 on bits 9..7 = r3..r1)
  ry_bf<2>(v, cs[33], sn[33]);
  ry_bf<1>(v, cs[34], sn[34]);
  ry_bf<0>(v, cs[35], sn[35]);
  cnot_rr<3, 2>(v);  // C11: ctrl bit9, tgt bit8
  cnot_rr<2, 1>(v);  // C12
  cnot_rr<1, 0>(v);  // C13
  ry_bf<3>(v, cs[53], sn[53]);
  ry_bf<2>(v, cs[54], sn[54]);
  ry_bf<1>(v, cs[55], sn[55]);

  // Exchange B -> C.
#pragma unroll
  for (int r = 0; r < 16; ++r)
    ex[SW(((tid >> 6) << 10) | (r << 6) | (tid & 63))] = v[r];
  __syncthreads();
  // ---- Layout C: regs r_j = x_{3+j} (r3=x6..r0=x3); tid[8:3]=x12..x7,
  //      tid[2:0]=x2..x0
#pragma unroll
  for (int r = 0; r < 16; ++r)
    v[r] = ex[SW(((tid >> 3) << 7) | (r << 3) | (tid & 7))];
  __syncthreads();

  // RY2 q15..q17 (p36..38 on bits 5..3 = r2..r0); C14..C16;
  // RY3 q14..q16 (p56..58 on bits 6..4 = r3..r1)
  ry_bf<2>(v, cs[36], sn[36]);
  ry_bf<1>(v, cs[37], sn[37]);
  ry_bf<0>(v, cs[38], sn[38]);
  cnot_rr<3, 2>(v);  // C14: ctrl bit6, tgt bit5
  cnot_rr<2, 1>(v);  // C15
  cnot_rr<1, 0>(v);  // C16
  ry_bf<3>(v, cs[56], sn[56]);
  ry_bf<2>(v, cs[57], sn[57]);
  ry_bf<1>(v, cs[58], sn[58]);

  // Exchange C -> D.
#pragma unroll
  for (int r = 0; r < 16; ++r)
    ex[SW(((tid >> 3) << 7) | (r << 3) | (tid & 7))] = v[r];
  __syncthreads();
  // ---- Layout D: regs r_j = x_j; tid = x12..x4
#pragma unroll
  for (int r = 0; r < 16; ++r) v[r] = ex[SW((tid << 4) | r)];

  // RY2 q18..q20 (p39..41 on bits 2..0 = r2..r0); C17..C19;
  // RY3 q17..q20 (p59..62 on bits 3..0)
  ry_bf<2>(v, cs[39], sn[39]);
  ry_bf<1>(v, cs[40], sn[40]);
  ry_bf<0>(v, cs[41], sn[41]);
  cnot_rr<3, 2>(v);  // C17: ctrl bit3, tgt bit2
  cnot_rr<2, 1>(v);  // C18
  cnot_rr<1, 0>(v);  // C19
  ry_bf<3>(v, cs[59], sn[59]);
  ry_bf<2>(v, cs[60], sn[60]);
  ry_bf<1>(v, cs[61], sn[61]);
  ry_bf<0>(v, cs[62], sn[62]);

  // Output: thread owns 16 consecutive elements (nontemporal 16B stores).
  const int base = (bid << 13) | (tid << 4);
  if (outmode == 2) {
    f32x4* o4 = (f32x4*)out;  // interleaved complex (re, 0)
#pragma unroll
    for (int i = 0; i < 8; ++i) {
      f32x4 w = {v[2 * i], 0.0f, v[2 * i + 1], 0.0f};
      __builtin_nontemporal_store(w, &o4[(base >> 1) + i]);
    }
  } else {
    f32x4* o4 = (f32x4*)(out + base);
#pragma unroll
    for (int j = 0; j < 4; ++j) {
      f32x4 w = {v[4 * j], v[4 * j + 1], v[4 * j + 2], v[4 * j + 3]};
      __builtin_nontemporal_store(w, &o4[j]);
    }
  }
}

extern "C" void kernel_launch(void* const* d_in, const int* in_sizes, int n_in,
                              void* d_out, int out_size, void* d_ws,
                              size_t ws_size, hipStream_t stream) {
  const float* p = (const float*)d_in[0];  // 63 fp32 params
  float* out = (float*)d_out;
  const int outmode = (out_size == 2 * NSTATE) ? 2 : 1;
  fused<<<256, 512, 0, stream>>>(p, out, outmode);
}

// Round 2
// 62.581 us; speedup vs baseline: 1.1011x; 1.1011x over previous
//
#include <hip/hip_runtime.h>

// 21-qubit HEA, fp32, all-real. ONE kernel, 256 blocks x 512 threads.
// R10: replace the phase-1 1024-dim shfl pre-sim (14 dependent ds_swizzle
// stages, ~224 swizzles) with a closed-form TRANSFER-MATRIX contraction.
// U1' = {RY2 q0..q8, C0..C7, RY3 q0..q7} on 9 sites (site q <-> bit
// z'_{8-q}); the CNOT staircase is the prefix-XOR permutation, so
// a(x12,c) = <z'*| RY3 . P . RY2 |Phi_c> contracts along the line with a
// 4-state transfer matrix over (s_q = d_0^..^d_q, b_q): ~170 scalar FMAs,
// block-uniform, zero cross-lane ops.
//   V0[s][b]   = R3_0[b*_0,s] * R2_0[s,b] * sel(p0,b)
//   T_q[(s',b')<-(s,b)] = R3_q[b*_q,s'] * R2_q[s^s',b'] * sel(pq,b^b')
//   site8:  a(x12,c) = sum_{s,b} R2_8[s^x12,c] * sel(p8,b^c) * w[s][b]
// with b*_q = bid_{7-q} (q=0..7), b*_8 = x12. Verified index-compatible
// with the previous (passing) shfl version: z'* = (bid<<1)|x12.
// W[x12][x11] = a(x12,0)*sel(p9,x11) + a(x12,1)*sel(p9,~x11)  (unchanged).
// Phase 2 (U2' on bits 12..0) is byte-identical to R9 (verified):
//   A: regs x12..x9, tid=x8..x0          : RY2 p30..32; C8..C10;  RY3 p50..52
//   B: regs x9..x6,  tid=x12..x10,x5..x0 : RY2 p33..35; C11..C13; RY3 p53..55
//   C: regs x6..x3,  tid=x12..x7,x2..x0  : RY2 p36..38; C14..C16; RY3 p56..58
//   D: regs x3..x0,  tid=x12..x4         : RY2 p39..41; C17..C19; RY3 p59..62
// launch_bounds(512,4): VGPR cap 128 -> 2 blocks/CU (4 waves/SIMD) for
// latency hiding; LDS 34KB/block also allows 2 blocks/CU.
// qubit q <-> bit 20-q; params RY1 q->p[q], RY2 q->p[21+q], RY3 q->p[42+q].
// Norm == 1 by unitarity.

#define NQ 21
#define NSTATE (1 << NQ)
#define SW(t) ((t) + ((t) >> 5))  // LDS anti-conflict: +1 word / 32 words

typedef float f32x4 __attribute__((ext_vector_type(4)));

__device__ __forceinline__ float sel(const float* cs, const float* sn, int i,
                                     int bit) {
  return bit ? sn[i] : cs[i];
}

template <int BIT, int N>
__device__ __forceinline__ void ry_bf(float (&v)[N], float c, float s) {
#pragma unroll
  for (int m = 0; m < N; ++m)
    if ((m & (1 << BIT)) == 0) {
      float a = v[m], b = v[m | (1 << BIT)];
      v[m] = c * a - s * b;
      v[m | (1 << BIT)] = s * a + c * b;
    }
}

template <int CBIT, int TBIT, int N>
__device__ __forceinline__ void cnot_rr(float (&v)[N]) {
#pragma unroll
  for (int m = 0; m < N; ++m)
    if ((m & (1 << CBIT)) && !(m & (1 << TBIT))) {
      float t = v[m];
      v[m] = v[m | (1 << TBIT)];
      v[m | (1 << TBIT)] = t;
    }
}

__global__ __launch_bounds__(512, 4) void fused(const float* __restrict__ p,
                                                float* __restrict__ out,
                                                int outmode) {
  __shared__ float cs[63], sn[63];
  __shared__ float ex[8448];    // 8192 + swizzle pad (max SW(8191)=8446)
  const int tid = threadIdx.x;  // 9 bits
  const int bid = blockIdx.x;   // 8 bits: bid_i = x_{13+i}
  if (tid < 63) {
    float h = 0.5f * p[tid];
    cs[tid] = cosf(h);
    sn[tid] = sinf(h);
  }
  __syncthreads();

  // ===== Phase 1: transfer-matrix contraction for a(x12,c) =====
  // w[s][b] carried as w00=w[0][0], w01=w[0][1], w10=w[1][0], w11=w[1][1].
  float W[2][2];
  {
    // site 0: b*_0 = bid bit 7
    const int b0 = (bid >> 7) & 1;
    const float c30 = cs[42], s30 = sn[42];
    const float r00 = b0 ? s30 : c30;
    const float r01 = b0 ? c30 : -s30;
    const float c20 = cs[21], s20 = sn[21];
    const float c10 = cs[0], s10 = sn[0];
    float w00 = r00 * c20 * c10;
    float w01 = r00 * (-s20) * s10;
    float w10 = r01 * s20 * c10;
    float w11 = r01 * c20 * s10;
#pragma unroll
    for (int q = 1; q <= 7; ++q) {
      const int bq = (bid >> (7 - q)) & 1;
      const float c1 = cs[q], s1 = sn[q];
      const float c2 = cs[21 + q], s2 = sn[21 + q];
      const float c3 = cs[42 + q], s3 = sn[42 + q];
      // h_{b'}[s] = sum_b sel(pq, b^b') * w[s][b]
      const float h00 = c1 * w00 + s1 * w01;  // b'=0, s=0
      const float h01 = c1 * w10 + s1 * w11;  // b'=0, s=1
      const float h10 = s1 * w00 + c1 * w01;  // b'=1, s=0
      const float h11 = s1 * w10 + c1 * w11;  // b'=1, s=1
      // m_{b'}[s'] = sum_s R2_q[s^s', b'] * h_{b'}[s]
      const float m00 = c2 * h00 + s2 * h01;   // b'=0, s'=0
      const float m01 = s2 * h00 + c2 * h01;   // b'=0, s'=1
      const float m10 = -s2 * h10 + c2 * h11;  // b'=1, s'=0
      const float m11 = c2 * h10 - s2 * h11;   // b'=1, s'=1
      // new[s'][b'] = R3_q[b*_q, s'] * m_{b'}[s']
      const float r0 = bq ? s3 : c3;
      const float r1 = bq ? c3 : -s3;
      w00 = r0 * m00;
      w01 = r0 * m10;
      w10 = r1 * m01;
      w11 = r1 * m11;
    }
    // site 8 boundary: a(x12,c) = sum_{s,b} R2_8[s^x12,c]*sel(p8,b^c)*w[s][b]
    const float c18 = cs[8], s18 = sn[8];
    const float c28 = cs[29], s28 = sn[29];
    const float hh00 = c18 * w00 + s18 * w01;  // c=0, s=0
    const float hh01 = c18 * w10 + s18 * w11;  // c=0, s=1
    const float hh10 = s18 * w00 + c18 * w01;  // c=1, s=0
    const float hh11 = s18 * w10 + c18 * w11;  // c=1, s=1
    const float a00 = c28 * hh00 + s28 * hh01;   // a(x12=0,c=0)
    const float a10 = s28 * hh00 + c28 * hh01;   // a(1,0)
    const float a01 = -s28 * hh10 + c28 * hh11;  // a(0,1)
    const float a11 = c28 * hh10 - s28 * hh11;   // a(1,1)
    // Boundary p9: W[x12][x11]
    W[0][0] = a00 * cs[9] + a01 * sn[9];
    W[0][1] = a00 * sn[9] + a01 * cs[9];
    W[1][0] = a10 * cs[9] + a11 * sn[9];
    W[1][1] = a10 * sn[9] + a11 * cs[9];
  }

  // ========== Phase 2 (U2' on bits 12..0) ==========
  float v[16];
  // ---- Layout A: regs r_j = x_{9+j} (r3=x12..r0=x9); tid = x8..x0.
  {
    const int gt = tid ^ (tid >> 1);  // bit b = x_b ^ x_{b+1}, b<8
    float tcommon = 1.0f;
#pragma unroll
    for (int b = 0; b < 8; ++b)
      tcommon *= sel(cs, sn, 20 - b, (gt >> b) & 1);
    const int t8 = (tid >> 8) & 1;  // x8
#pragma unroll
    for (int r = 0; r < 16; ++r) {
      const int gr = r ^ (r >> 1);  // gr_0 = x9^x10, gr_1 = x10^x11
      float prod = tcommon * W[(r >> 3) & 1][(r >> 2) & 1];
      prod *= sel(cs, sn, 12, t8 ^ (r & 1));   // s8 = x8 ^ x9
      prod *= sel(cs, sn, 11, gr & 1);         // s9
      prod *= sel(cs, sn, 10, (gr >> 1) & 1);  // s10 (s11 folded into W)
      v[r] = prod;
    }
  }

  // RY2 q9..q11 (p30..32 on bits 11..9 = r2..r0); C8..C10;
  // RY3 q8..q10 (p50..52 on bits 12..10 = r3..r1)
  ry_bf<2>(v, cs[30], sn[30]);
  ry_bf<1>(v, cs[31], sn[31]);
  ry_bf<0>(v, cs[32], sn[32]);
  cnot_rr<3, 2>(v);  // C8:  ctrl bit12, tgt bit11
  cnot_rr<2, 1>(v);  // C9
  cnot_rr<1, 0>(v);  // C10
  ry_bf<3>(v, cs[50], sn[50]);
  ry_bf<2>(v, cs[51], sn[51]);
  ry_bf<1>(v, cs[52], sn[52]);

  // Exchange A -> B. Canonical t = x12..x0.
#pragma unroll
  for (int r = 0; r < 16; ++r) ex[SW((r << 9) | tid)] = v[r];
  __syncthreads();
  // ---- Layout B: regs r_j = x_{6+j}; tid[8:6]=x12..x10, tid[5:0]=x5..x0
#pragma unroll
  for (int r = 0; r < 16; ++r)
    v[r] = ex[SW(((tid >> 6) << 10) | (r << 6) | (tid & 63))];
  __syncthreads();

  // RY2 q12..q14 (p33..35 on bits 8..6 = r2..r0); C11..C13;
  // RY3 q11..q13 (p53..55 on bits 9..7 = r3..r1)
  ry_bf<2>(v, cs[33], sn[33]);
  ry_bf<1>(v, cs[34], sn[34]);
  ry_bf<0>(v, cs[35], sn[35]);
  cnot_rr<3, 2>(v);  // C11: ctrl bit9, tgt bit8
  cnot_rr<2, 1>(v);  // C12
  cnot_rr<1, 0>(v);  // C13
  ry_bf<3>(v, cs[53], sn[53]);
  ry_bf<2>(v, cs[54], sn[54]);
  ry_bf<1>(v, cs[55], sn[55]);

  // Exchange B -> C.
#pragma unroll
  for (int r = 0; r < 16; ++r)
    ex[SW(((tid >> 6) << 10) | (r << 6) | (tid & 63))] = v[r];
  __syncthreads();
  // ---- Layout C: regs r_j = x_{3+j} (r3=x6..r0=x3); tid[8:3]=x12..x7,
  //      tid[2:0]=x2..x0
#pragma unroll
  for (int r = 0; r < 16; ++r)
    v[r] = ex[SW(((tid >> 3) << 7) | (r << 3) | (tid & 7))];
  __syncthreads();

  // RY2 q15..q17 (p36..38 on bits 5..3 = r2..r0); C14..C16;
  // RY3 q14..q16 (p56..58 on bits 6..4 = r3..r1)
  ry_bf<2>(v, cs[36], sn[36]);
  ry_bf<1>(v, cs[37], sn[37]);
  ry_bf<0>(v, cs[38], sn[38]);
  cnot_rr<3, 2>(v);  // C14: ctrl bit6, tgt bit5
  cnot_rr<2, 1>(v);  // C15
  cnot_rr<1, 0>(v);  // C16
  ry_bf<3>(v, cs[56], sn[56]);
  ry_bf<2>(v, cs[57], sn[57]);
  ry_bf<1>(v, cs[58], sn[58]);

  // Exchange C -> D.
#pragma unroll
  for (int r = 0; r < 16; ++r)
    ex[SW(((tid >> 3) << 7) | (r << 3) | (tid & 7))] = v[r];
  __syncthreads();
  // ---- Layout D: regs r_j = x_j; tid = x12..x4
#pragma unroll
  for (int r = 0; r < 16; ++r) v[r] = ex[SW((tid << 4) | r)];

  // RY2 q18..q20 (p39..41 on bits 2..0 = r2..r0); C17..C19;
  // RY3 q17..q20 (p59..62 on bits 3..0)
  ry_bf<2>(v, cs[39], sn[39]);
  ry_bf<1>(v, cs[40], sn[40]);
  ry_bf<0>(v, cs[41], sn[41]);
  cnot_rr<3, 2>(v);  // C17: ctrl bit3, tgt bit2
  cnot_rr<2, 1>(v);  // C18
  cnot_rr<1, 0>(v);  // C19
  ry_bf<3>(v, cs[59], sn[59]);
  ry_bf<2>(v, cs[60], sn[60]);
  ry_bf<1>(v, cs[61], sn[61]);
  ry_bf<0>(v, cs[62], sn[62]);

  // Output: thread owns 16 consecutive elements (nontemporal 16B stores).
  const int base = (bid << 13) | (tid << 4);
  if (outmode == 2) {
    f32x4* o4 = (f32x4*)out;  // interleaved complex (re, 0)
#pragma unroll
    for (int i = 0; i < 8; ++i) {
      f32x4 w = {v[2 * i], 0.0f, v[2 * i + 1], 0.0f};
      __builtin_nontemporal_store(w, &o4[(base >> 1) + i]);
    }
  } else {
    f32x4* o4 = (f32x4*)(out + base);
#pragma unroll
    for (int j = 0; j < 4; ++j) {
      f32x4 w = {v[4 * j], v[4 * j + 1], v[4 * j + 2], v[4 * j + 3]};
      __builtin_nontemporal_store(w, &o4[j]);
    }
  }
}

extern "C" void kernel_launch(void* const* d_in, const int* in_sizes, int n_in,
                              void* d_out, int out_size, void* d_ws,
                              size_t ws_size, hipStream_t stream) {
  const float* p = (const float*)d_in[0];  // 63 fp32 params
  float* out = (float*)d_out;
  const int outmode = (out_size == 2 * NSTATE) ? 2 : 1;
  fused<<<256, 512, 0, stream>>>(p, out, outmode);
}

// Round 3
// 61.809 us; speedup vs baseline: 1.1148x; 1.0125x over previous
//
#include <hip/hip_runtime.h>

// 21-qubit HEA, fp32, all-real. ONE kernel, 256 blocks x 512 threads.
// R11 = R10 + LDS diet: (a) (cos,sin) interleaved as float2 so every
// coefficient fetch is one ds_read_b64 broadcast; (b) init-product sel()
// converted from per-lane LDS reads to register selects (r is
// unroll-constant -> compile-time picks; only the t8 term needs cndmask);
// (c) ping-pong exchange buffers ex[2] (68KB LDS, legal on gfx950) drop
// the read->write barrier of each exchange: 7 barriers -> 4.
// All layout math / gate ledger / SW swizzle byte-identical to R10:
// U1' = {RY2 q0..q8, C0..C7, RY3 q0..q7} (bits 20..12) via 4-state
// transfer matrix -> a(x12,c); W[x12][x11] = a(x12,0)*sel(p9,x11) +
// a(x12,1)*sel(p9,~x11). U2' (bits 12..0) over 4 layouts:
//   A: regs x12..x9, tid=x8..x0          : RY2 p30..32; C8..C10;  RY3 p50..52
//   B: regs x9..x6,  tid=x12..x10,x5..x0 : RY2 p33..35; C11..C13; RY3 p53..55
//   C: regs x6..x3,  tid=x12..x7,x2..x0  : RY2 p36..38; C14..C16; RY3 p56..58
//   D: regs x3..x0,  tid=x12..x4         : RY2 p39..41; C17..C19; RY3 p59..62
// Ping-pong safety: exch1 uses ex[0] (w,B1,r), exch2 ex[1] (w,B2,r),
// exch3 ex[0] (w,B3,r). All ex[0] reads of exch1 precede B2 (program
// order: each thread reads ex[0] before writing ex[1] before B2), so
// re-writing ex[0] after B2 is race-free. Same for ex[1] reads before B3.
// qubit q <-> bit 20-q; params RY1 q->p[q], RY2 q->p[21+q], RY3 q->p[42+q].
// Norm == 1 by unitarity.

#define NQ 21
#define NSTATE (1 << NQ)
#define SW(t) ((t) + ((t) >> 5))  // LDS anti-conflict: +1 word / 32 words

typedef float f32x4 __attribute__((ext_vector_type(4)));

template <int BIT, int N>
__device__ __forceinline__ void ry_bf(float (&v)[N], float c, float s) {
#pragma unroll
  for (int m = 0; m < N; ++m)
    if ((m & (1 << BIT)) == 0) {
      float a = v[m], b = v[m | (1 << BIT)];
      v[m] = c * a - s * b;
      v[m | (1 << BIT)] = s * a + c * b;
    }
}

template <int CBIT, int TBIT, int N>
__device__ __forceinline__ void cnot_rr(float (&v)[N]) {
#pragma unroll
  for (int m = 0; m < N; ++m)
    if ((m & (1 << CBIT)) && !(m & (1 << TBIT))) {
      float t = v[m];
      v[m] = v[m | (1 << TBIT)];
      v[m | (1 << TBIT)] = t;
    }
}

__global__ __launch_bounds__(512, 4) void fused(const float* __restrict__ p,
                                                float* __restrict__ out,
                                                int outmode) {
  __shared__ float2 csn[63];    // (cos, sin) pairs -> b64 broadcast reads
  __shared__ float ex[2][8448];  // ping-pong; 8192 + swizzle pad each
  const int tid = threadIdx.x;   // 9 bits
  const int bid = blockIdx.x;    // 8 bits: bid_i = x_{13+i}
  if (tid < 63) {
    float h = 0.5f * p[tid];
    csn[tid] = float2{__cosf(h) * 0.0f + cosf(h), sinf(h)};
  }
  __syncthreads();  // B0

  // ===== Phase 1: transfer-matrix contraction for a(x12,c) =====
  float W[2][2];
  {
    const int b0 = (bid >> 7) & 1;
    const float2 g30 = csn[42], g20 = csn[21], g10 = csn[0];
    const float r00 = b0 ? g30.y : g30.x;
    const float r01 = b0 ? g30.x : -g30.y;
    float w00 = r00 * g20.x * g10.x;
    float w01 = r00 * (-g20.y) * g10.y;
    float w10 = r01 * g20.y * g10.x;
    float w11 = r01 * g20.x * g10.y;
#pragma unroll
    for (int q = 1; q <= 7; ++q) {
      const int bq = (bid >> (7 - q)) & 1;
      const float2 g1 = csn[q], g2 = csn[21 + q], g3 = csn[42 + q];
      const float c1 = g1.x, s1 = g1.y;
      const float c2 = g2.x, s2 = g2.y;
      const float c3 = g3.x, s3 = g3.y;
      const float h00 = c1 * w00 + s1 * w01;
      const float h01 = c1 * w10 + s1 * w11;
      const float h10 = s1 * w00 + c1 * w01;
      const float h11 = s1 * w10 + c1 * w11;
      const float m00 = c2 * h00 + s2 * h01;
      const float m01 = s2 * h00 + c2 * h01;
      const float m10 = -s2 * h10 + c2 * h11;
      const float m11 = c2 * h10 - s2 * h11;
      const float r0 = bq ? s3 : c3;
      const float r1 = bq ? c3 : -s3;
      w00 = r0 * m00;
      w01 = r0 * m10;
      w10 = r1 * m01;
      w11 = r1 * m11;
    }
    const float2 g18 = csn[8], g28 = csn[29], g9 = csn[9];
    const float hh00 = g18.x * w00 + g18.y * w01;
    const float hh01 = g18.x * w10 + g18.y * w11;
    const float hh10 = g18.y * w00 + g18.x * w01;
    const float hh11 = g18.y * w10 + g18.x * w11;
    const float a00 = g28.x * hh00 + g28.y * hh01;
    const float a10 = g28.y * hh00 + g28.x * hh01;
    const float a01 = -g28.y * hh10 + g28.x * hh11;
    const float a11 = g28.x * hh10 - g28.y * hh11;
    W[0][0] = a00 * g9.x + a01 * g9.y;
    W[0][1] = a00 * g9.y + a01 * g9.x;
    W[1][0] = a10 * g9.x + a11 * g9.y;
    W[1][1] = a10 * g9.y + a11 * g9.x;
  }

  // ========== Phase 2 (U2' on bits 12..0) ==========
  float v[16];
  // ---- Layout A: regs r_j = x_{9+j} (r3=x12..r0=x9); tid = x8..x0.
  {
    const int gt = tid ^ (tid >> 1);  // bit b = x_b ^ x_{b+1}, b<8
    float tcommon = 1.0f;
#pragma unroll
    for (int b = 0; b < 8; ++b) {
      const float2 gb = csn[20 - b];
      tcommon *= ((gt >> b) & 1) ? gb.y : gb.x;
    }
    const float2 g12 = csn[12], g11 = csn[11], g10 = csn[10];
    const int t8 = (tid >> 8) & 1;  // x8
    const float s12_0 = t8 ? g12.y : g12.x;  // r&1==0: bit = x8^0
    const float s12_1 = t8 ? g12.x : g12.y;  // r&1==1: bit = x8^1
#pragma unroll
    for (int r = 0; r < 16; ++r) {
      const int gr = r ^ (r >> 1);  // compile-time per r
      float prod = tcommon * W[(r >> 3) & 1][(r >> 2) & 1];
      prod *= (r & 1) ? s12_1 : s12_0;            // s8 = x8 ^ x9
      prod *= (gr & 1) ? g11.y : g11.x;           // s9  (compile-time pick)
      prod *= ((gr >> 1) & 1) ? g10.y : g10.x;    // s10 (compile-time pick)
      v[r] = prod;
    }
  }

  // RY2 q9..q11 (p30..32 on bits 11..9 = r2..r0); C8..C10;
  // RY3 q8..q10 (p50..52 on bits 12..10 = r3..r1)
  ry_bf<2>(v, csn[30].x, csn[30].y);
  ry_bf<1>(v, csn[31].x, csn[31].y);
  ry_bf<0>(v, csn[32].x, csn[32].y);
  cnot_rr<3, 2>(v);  // C8
  cnot_rr<2, 1>(v);  // C9
  cnot_rr<1, 0>(v);  // C10
  ry_bf<3>(v, csn[50].x, csn[50].y);
  ry_bf<2>(v, csn[51].x, csn[51].y);
  ry_bf<1>(v, csn[52].x, csn[52].y);

  // Exchange A -> B via ex[0]. Canonical t = x12..x0.
#pragma unroll
  for (int r = 0; r < 16; ++r) ex[0][SW((r << 9) | tid)] = v[r];
  __syncthreads();  // B1
#pragma unroll
  for (int r = 0; r < 16; ++r)
    v[r] = ex[0][SW(((tid >> 6) << 10) | (r << 6) | (tid & 63))];

  // RY2 q12..q14 (p33..35 on bits 8..6 = r2..r0); C11..C13;
  // RY3 q11..q13 (p53..55 on bits 9..7 = r3..r1)
  ry_bf<2>(v, csn[33].x, csn[33].y);
  ry_bf<1>(v, csn[34].x, csn[34].y);
  ry_bf<0>(v, csn[35].x, csn[35].y);
  cnot_rr<3, 2>(v);  // C11
  cnot_rr<2, 1>(v);  // C12
  cnot_rr<1, 0>(v);  // C13
  ry_bf<3>(v, csn[53].x, csn[53].y);
  ry_bf<2>(v, csn[54].x, csn[54].y);
  ry_bf<1>(v, csn[55].x, csn[55].y);

  // Exchange B -> C via ex[1].
#pragma unroll
  for (int r = 0; r < 16; ++r)
    ex[1][SW(((tid >> 6) << 10) | (r << 6) | (tid & 63))] = v[r];
  __syncthreads();  // B2  (also fences all ex[0] reads above)
#pragma unroll
  for (int r = 0; r < 16; ++r)
    v[r] = ex[1][SW(((tid >> 3) << 7) | (r << 3) | (tid & 7))];

  // RY2 q15..q17 (p36..38 on bits 5..3 = r2..r0); C14..C16;
  // RY3 q14..q16 (p56..58 on bits 6..4 = r3..r1)
  ry_bf<2>(v, csn[36].x, csn[36].y);
  ry_bf<1>(v, csn[37].x, csn[37].y);
  ry_bf<0>(v, csn[38].x, csn[38].y);
  cnot_rr<3, 2>(v);  // C14
  cnot_rr<2, 1>(v);  // C15
  cnot_rr<1, 0>(v);  // C16
  ry_bf<3>(v, csn[56].x, csn[56].y);
  ry_bf<2>(v, csn[57].x, csn[57].y);
  ry_bf<1>(v, csn[58].x, csn[58].y);

  // Exchange C -> D via ex[0] (safe: all ex[0] reads preceded B2).
#pragma unroll
  for (int r = 0; r < 16; ++r)
    ex[0][SW(((tid >> 3) << 7) | (r << 3) | (tid & 7))] = v[r];
  __syncthreads();  // B3
#pragma unroll
  for (int r = 0; r < 16; ++r) v[r] = ex[0][SW((tid << 4) | r)];

  // RY2 q18..q20 (p39..41 on bits 2..0 = r2..r0); C17..C19;
  // RY3 q17..q20 (p59..62 on bits 3..0)
  ry_bf<2>(v, csn[39].x, csn[39].y);
  ry_bf<1>(v, csn[40].x, csn[40].y);
  ry_bf<0>(v, csn[41].x, csn[41].y);
  cnot_rr<3, 2>(v);  // C17
  cnot_rr<2, 1>(v);  // C18
  cnot_rr<1, 0>(v);  // C19
  ry_bf<3>(v, csn[59].x, csn[59].y);
  ry_bf<2>(v, csn[60].x, csn[60].y);
  ry_bf<1>(v, csn[61].x, csn[61].y);
  ry_bf<0>(v, csn[62].x, csn[62].y);

  // Output: thread owns 16 consecutive elements (nontemporal 16B stores).
  const int base = (bid << 13) | (tid << 4);
  if (outmode == 2) {
    f32x4* o4 = (f32x4*)out;  // interleaved complex (re, 0)
#pragma unroll
    for (int i = 0; i < 8; ++i) {
      f32x4 w = {v[2 * i], 0.0f, v[2 * i + 1], 0.0f};
      __builtin_nontemporal_store(w, &o4[(base >> 1) + i]);
    }
  } else {
    f32x4* o4 = (f32x4*)(out + base);
#pragma unroll
    for (int j = 0; j < 4; ++j) {
      f32x4 w = {v[4 * j], v[4 * j + 1], v[4 * j + 2], v[4 * j + 3]};
      __builtin_nontemporal_store(w, &o4[j]);
    }
  }
}

extern "C" void kernel_launch(void* const* d_in, const int* in_sizes, int n_in,
                              void* d_out, int out_size, void* d_ws,
                              size_t ws_size, hipStream_t stream) {
  const float* p = (const float*)d_in[0];  // 63 fp32 params
  float* out = (float*)d_out;
  const int outmode = (out_size == 2 * NSTATE) ? 2 : 1;
  fused<<<256, 512, 0, stream>>>(p, out, outmode);
}

// Round 4
// 59.875 us; speedup vs baseline: 1.1508x; 1.0323x over previous
//
#include <hip/hip_runtime.h>

// 21-qubit HEA, fp32, all-real. ONE kernel, 1024 blocks x 256 threads.
// R12: occupancy rewrite. R1/R3 nulls + R2 win diagnose the kernel as
// LATENCY-bound at 2 waves/SIMD (2^21/16 regs = 512 thr/CU fixed). Halve
// the register tile (v[16] -> v[8]) so total threads double: 2^18 threads
// = 16 waves/CU (4/SIMD), 4 independent 256-thread blocks co-resident per
// CU; their barrier/exchange phases interleave and hide latency.
// Boundary moves bit 12 -> bit 10 (index-shift of verified R11 machinery):
//   U1''' = {RY2 q0..q10, C0..C9, RY3 q0..q9}   acts on bits 20..10,
//   U2''' = {RY2 q11..q20, C10..C19, RY3 q10..q20} acts on bits 10..0.
// Commutation: RY2 q11..20 (bits 9..0) move right past C0..C9 (bits
// 20..10); RY3 q0..q9 (bits 20..11) move left past C10..C19 (bits 10..0).
// U1''' -> a(x10,c) via 11-site 4-state transfer matrix (block-uniform,
// ~210 FMA, zero cross-lane): sites q0..q9 full steps (b*_q = bid_{9-q},
// bid = x20..x11, 10 bits), site 10 boundary (RY1 csn[10], RY2 csn[31]);
// W[x10][x9] = a(x10,0)*sel(p11,x9) + a(x10,1)*sel(p11,~x9).
// U2''' over 5 layouts (regs 3 bits, 1-bit overlap), canonical t=x10..x0:
//   A: regs x10..x8, tid=x7..x0          : RY2 p32,33; C10,C11; RY3 p52,53
//   B: regs x8..x6,  tid=[x10 x9][x5..x0]: RY2 p34,35; C12,C13; RY3 p54,55
//   C: regs x6..x4,  tid=[x10..x7][x3..x0]:RY2 p36,37; C14,C15; RY3 p56,57
//   D: regs x4..x2,  tid=[x10..x5][x1 x0]: RY2 p38,39; C16,C17; RY3 p58,59
//   E: regs x2..x0,  tid=x10..x3         : RY2 p40,41; C18,C19; RY3 p60..62
// Ledger (all 63 params audited): RY1 p0..p10 TM, p11 W, p12..p20 init-A;
// RY2 p21..p31 TM, p32..41 stages (each precedes first CNOT on its bit);
// RY3 p42..p51 TM, p52..62 stages (each follows last CNOT on its bit);
// CNOT C0..C9 TM prefix-xor, C10..C19 stages (2/stage).
// Ping-pong ex[2]: A->B ex0, B->C ex1, C->D ex0, D->E ex1; re-write of a
// buffer is always after the barrier that followed its last reads.
// qubit q <-> bit 20-q; params RY1 q->p[q], RY2 q->p[21+q], RY3 q->p[42+q].
// Norm == 1 by unitarity.

#define NQ 21
#define NSTATE (1 << NQ)
#define SW(t) ((t) + ((t) >> 5))  // LDS anti-conflict: +1 word / 32 words

typedef float f32x4 __attribute__((ext_vector_type(4)));

template <int BIT, int N>
__device__ __forceinline__ void ry_bf(float (&v)[N], float c, float s) {
#pragma unroll
  for (int m = 0; m < N; ++m)
    if ((m & (1 << BIT)) == 0) {
      float a = v[m], b = v[m | (1 << BIT)];
      v[m] = c * a - s * b;
      v[m | (1 << BIT)] = s * a + c * b;
    }
}

template <int CBIT, int TBIT, int N>
__device__ __forceinline__ void cnot_rr(float (&v)[N]) {
#pragma unroll
  for (int m = 0; m < N; ++m)
    if ((m & (1 << CBIT)) && !(m & (1 << TBIT))) {
      float t = v[m];
      v[m] = v[m | (1 << TBIT)];
      v[m | (1 << TBIT)] = t;
    }
}

__global__ __launch_bounds__(256, 4) void fused(const float* __restrict__ p,
                                                float* __restrict__ out,
                                                int outmode) {
  __shared__ float2 csn[63];     // (cos, sin) pairs -> b64 broadcast reads
  __shared__ float ex[2][2112];  // ping-pong; 2048 + swizzle pad each
  const int tid = threadIdx.x;   // 8 bits
  const int bid = blockIdx.x;    // 10 bits: bid_i = x_{11+i}
  if (tid < 63) {
    float h = 0.5f * p[tid];
    csn[tid] = float2{cosf(h), sinf(h)};
  }
  __syncthreads();  // B0

  // ===== Phase 1: 11-site transfer-matrix contraction for a(x10,c) =====
  float W[2][2];
  {
    const int b0 = (bid >> 9) & 1;
    const float2 g30 = csn[42], g20 = csn[21], g10 = csn[0];
    const float r00 = b0 ? g30.y : g30.x;
    const float r01 = b0 ? g30.x : -g30.y;
    float w00 = r00 * g20.x * g10.x;
    float w01 = r00 * (-g20.y) * g10.y;
    float w10 = r01 * g20.y * g10.x;
    float w11 = r01 * g20.x * g10.y;
#pragma unroll
    for (int q = 1; q <= 9; ++q) {
      const int bq = (bid >> (9 - q)) & 1;
      const float2 g1 = csn[q], g2 = csn[21 + q], g3 = csn[42 + q];
      const float c1 = g1.x, s1 = g1.y;
      const float c2 = g2.x, s2 = g2.y;
      const float c3 = g3.x, s3 = g3.y;
      const float h00 = c1 * w00 + s1 * w01;
      const float h01 = c1 * w10 + s1 * w11;
      const float h10 = s1 * w00 + c1 * w01;
      const float h11 = s1 * w10 + c1 * w11;
      const float m00 = c2 * h00 + s2 * h01;
      const float m01 = s2 * h00 + c2 * h01;
      const float m10 = -s2 * h10 + c2 * h11;
      const float m11 = c2 * h10 - s2 * h11;
      const float r0 = bq ? s3 : c3;
      const float r1 = bq ? c3 : -s3;
      w00 = r0 * m00;
      w01 = r0 * m10;
      w10 = r1 * m01;
      w11 = r1 * m11;
    }
    // boundary site 10: RY1 p10, RY2 q10 = p31; then W-coupling RY1 p11
    const float2 g1b = csn[10], g2b = csn[31], gW = csn[11];
    const float hh00 = g1b.x * w00 + g1b.y * w01;
    const float hh01 = g1b.x * w10 + g1b.y * w11;
    const float hh10 = g1b.y * w00 + g1b.x * w01;
    const float hh11 = g1b.y * w10 + g1b.x * w11;
    const float a00 = g2b.x * hh00 + g2b.y * hh01;
    const float a10 = g2b.y * hh00 + g2b.x * hh01;
    const float a01 = -g2b.y * hh10 + g2b.x * hh11;
    const float a11 = g2b.x * hh10 - g2b.y * hh11;
    W[0][0] = a00 * gW.x + a01 * gW.y;
    W[0][1] = a00 * gW.y + a01 * gW.x;
    W[1][0] = a10 * gW.x + a11 * gW.y;
    W[1][1] = a10 * gW.y + a11 * gW.x;
  }

  // ========== Phase 2 (U2''' on bits 10..0) ==========
  float v[8];
  // ---- Layout A: regs r_j = x_{8+j} (r2=x10..r0=x8); tid = x7..x0.
  {
    const int gt = tid ^ (tid >> 1);  // bits b=0..6: x_b ^ x_{b+1}
    float tcommon = 1.0f;
#pragma unroll
    for (int b = 0; b < 7; ++b) {
      const float2 gb = csn[20 - b];
      tcommon *= ((gt >> b) & 1) ? gb.y : gb.x;
    }
    const int t7 = (tid >> 7) & 1;           // x7
    const float2 g13 = csn[13], g12 = csn[12];
    const float s13_0 = t7 ? g13.y : g13.x;  // link x7^x8, r0=0
    const float s13_1 = t7 ? g13.x : g13.y;  // link x7^x8, r0=1
#pragma unroll
    for (int r = 0; r < 8; ++r) {
      const int gr = r ^ (r >> 1);  // gr_0 = x8^x9 (compile-time per r)
      float prod = tcommon * W[(r >> 2) & 1][(r >> 1) & 1];
      prod *= (r & 1) ? s13_1 : s13_0;   // p13: x7^x8
      prod *= (gr & 1) ? g12.y : g12.x;  // p12: x8^x9 (p11 folded into W)
      v[r] = prod;
    }
  }

  // Stage A: RY2 q11,q12 (p32 bit9=r1, p33 bit8=r0); C10,C11;
  //          RY3 q10,q11 (p52 bit10=r2, p53 bit9=r1)
  ry_bf<1>(v, csn[32].x, csn[32].y);
  ry_bf<0>(v, csn[33].x, csn[33].y);
  cnot_rr<2, 1>(v);  // C10
  cnot_rr<1, 0>(v);  // C11
  ry_bf<2>(v, csn[52].x, csn[52].y);
  ry_bf<1>(v, csn[53].x, csn[53].y);

  // Exchange A -> B via ex[0]. Canonical t = x10..x0.
#pragma unroll
  for (int r = 0; r < 8; ++r) ex[0][SW((r << 8) | tid)] = v[r];
  __syncthreads();  // B1
#pragma unroll
  for (int r = 0; r < 8; ++r)
    v[r] = ex[0][SW(((tid >> 6) << 9) | (r << 6) | (tid & 63))];

  // Stage B: RY2 q13,q14 (p34 bit7=r1, p35 bit6=r0); C12,C13;
  //          RY3 q12,q13 (p54 bit8=r2, p55 bit7=r1)
  ry_bf<1>(v, csn[34].x, csn[34].y);
  ry_bf<0>(v, csn[35].x, csn[35].y);
  cnot_rr<2, 1>(v);  // C12
  cnot_rr<1, 0>(v);  // C13
  ry_bf<2>(v, csn[54].x, csn[54].y);
  ry_bf<1>(v, csn[55].x, csn[55].y);

  // Exchange B -> C via ex[1].
#pragma unroll
  for (int r = 0; r < 8; ++r)
    ex[1][SW(((tid >> 6) << 9) | (r << 6) | (tid & 63))] = v[r];
  __syncthreads();  // B2  (also fences exchange-1's ex[0] reads)
#pragma unroll
  for (int r = 0; r < 8; ++r)
    v[r] = ex[1][SW(((tid >> 4) << 7) | (r << 4) | (tid & 15))];

  // Stage C: RY2 q15,q16 (p36 bit5=r1, p37 bit4=r0); C14,C15;
  //          RY3 q14,q15 (p56 bit6=r2, p57 bit5=r1)
  ry_bf<1>(v, csn[36].x, csn[36].y);
  ry_bf<0>(v, csn[37].x, csn[37].y);
  cnot_rr<2, 1>(v);  // C14
  cnot_rr<1, 0>(v);  // C15
  ry_bf<2>(v, csn[56].x, csn[56].y);
  ry_bf<1>(v, csn[57].x, csn[57].y);

  // Exchange C -> D via ex[0] (safe: its exchange-1 reads preceded B2).
#pragma unroll
  for (int r = 0; r < 8; ++r)
    ex[0][SW(((tid >> 4) << 7) | (r << 4) | (tid & 15))] = v[r];
  __syncthreads();  // B3  (also fences exchange-2's ex[1] reads)
#pragma unroll
  for (int r = 0; r < 8; ++r)
    v[r] = ex[0][SW(((tid >> 2) << 5) | (r << 2) | (tid & 3))];

  // Stage D: RY2 q17,q18 (p38 bit3=r1, p39 bit2=r0); C16,C17;
  //          RY3 q16,q17 (p58 bit4=r2, p59 bit3=r1)
  ry_bf<1>(v, csn[38].x, csn[38].y);
  ry_bf<0>(v, csn[39].x, csn[39].y);
  cnot_rr<2, 1>(v);  // C16
  cnot_rr<1, 0>(v);  // C17
  ry_bf<2>(v, csn[58].x, csn[58].y);
  ry_bf<1>(v, csn[59].x, csn[59].y);

  // Exchange D -> E via ex[1] (safe: its exchange-2 reads preceded B3).
#pragma unroll
  for (int r = 0; r < 8; ++r)
    ex[1][SW(((tid >> 2) << 5) | (r << 2) | (tid & 3))] = v[r];
  __syncthreads();  // B4
#pragma unroll
  for (int r = 0; r < 8; ++r) v[r] = ex[1][SW((tid << 3) | r)];

  // Stage E: RY2 q19,q20 (p40 bit1=r1, p41 bit0=r0); C18,C19;
  //          RY3 q18,q19,q20 (p60 bit2, p61 bit1, p62 bit0)
  ry_bf<1>(v, csn[40].x, csn[40].y);
  ry_bf<0>(v, csn[41].x, csn[41].y);
  cnot_rr<2, 1>(v);  // C18
  cnot_rr<1, 0>(v);  // C19
  ry_bf<2>(v, csn[60].x, csn[60].y);
  ry_bf<1>(v, csn[61].x, csn[61].y);
  ry_bf<0>(v, csn[62].x, csn[62].y);

  // Output: thread owns 8 consecutive elements (nontemporal 16B stores).
  const int base = (bid << 11) | (tid << 3);
  if (outmode == 2) {
    f32x4* o4 = (f32x4*)out;  // interleaved complex (re, 0)
#pragma unroll
    for (int i = 0; i < 4; ++i) {
      f32x4 w = {v[2 * i], 0.0f, v[2 * i + 1], 0.0f};
      __builtin_nontemporal_store(w, &o4[(base >> 1) + i]);
    }
  } else {
    f32x4* o4 = (f32x4*)(out + base);
#pragma unroll
    for (int j = 0; j < 2; ++j) {
      f32x4 w = {v[4 * j], v[4 * j + 1], v[4 * j + 2], v[4 * j + 3]};
      __builtin_nontemporal_store(w, &o4[j]);
    }
  }
}

extern "C" void kernel_launch(void* const* d_in, const int* in_sizes, int n_in,
                              void* d_out, int out_size, void* d_ws,
                              size_t ws_size, hipStream_t stream) {
  const float* p = (const float*)d_in[0];  // 63 fp32 params
  float* out = (float*)d_out;
  const int outmode = (out_size == 2 * NSTATE) ? 2 : 1;
  fused<<<1024, 256, 0, stream>>>(p, out, outmode);
}